// Round 3
// baseline (692.342 us; speedup 1.0000x reference)
//
#include <hip/hip_runtime.h>
#include <hip/hip_bf16.h>
#include <math.h>

// B=128 rows, D=512*512=262144. dots[i][j]=X[i]·Y[j]; sim[j][i]=dots/(|X_i||Y_j|);
// outputs top1/top10 retrieval accuracy.
//
// R2 change: cross-block atomicAdd combine (269 MB of write-through HBM traffic,
// 512-way same-address serialization — rocprof WRITE_SIZE smoking gun) replaced
// with per-block partial C tiles in d_ws + a reduce kernel. NBLK picked from
// ws_size at launch (constant across calls). Norms keep atomics (256 addrs, cheap).

#define DIMD 262144
#define BK   16
#define LSTR 132   // LDS row stride: float4-aligned + bank rotation

// ---------------- main GEMM: one block = one K-chunk, full 128x128 C tile ----
__global__ __launch_bounds__(256)
void dot_norm_partial(const float* __restrict__ Z, const float* __restrict__ Y,
                      float* __restrict__ partials, float* __restrict__ norms,
                      int KC) {
    __shared__ float lA[BK][LSTR];
    __shared__ float lB[BK][LSTR];

    const int tid = threadIdx.x;
    const int tx = tid & 15;
    const int ty = tid >> 4;
    const int r0 = ty * 8;
    const int c0 = tx * 8;
    const int rowm = tid >> 2;   // 0..63 (second slot rowm+64)
    const int kq   = tid & 3;

    float acc[8][8];
#pragma unroll
    for (int i = 0; i < 8; ++i)
#pragma unroll
        for (int j = 0; j < 8; ++j) acc[i][j] = 0.f;

    float a2s0 = 0.f, a2s1 = 0.f, b2s0 = 0.f, b2s1 = 0.f;

    const size_t kbase = (size_t)blockIdx.x * KC;
    const size_t offA0 = (size_t)rowm * DIMD + kbase + kq * 4;
    const size_t offA1 = (size_t)(rowm + 64) * DIMD + kbase + kq * 4;
    const int niter = KC / BK;

#pragma unroll 1
    for (int t = 0; t < niter; ++t) {
        const size_t ko = (size_t)t * BK;
        const float4 av0 = *(const float4*)(Z + offA0 + ko);
        const float4 av1 = *(const float4*)(Z + offA1 + ko);
        const float4 bv0 = *(const float4*)(Y + offA0 + ko);
        const float4 bv1 = *(const float4*)(Y + offA1 + ko);

        a2s0 += av0.x*av0.x + av0.y*av0.y + av0.z*av0.z + av0.w*av0.w;
        a2s1 += av1.x*av1.x + av1.y*av1.y + av1.z*av1.z + av1.w*av1.w;
        b2s0 += bv0.x*bv0.x + bv0.y*bv0.y + bv0.z*bv0.z + bv0.w*bv0.w;
        b2s1 += bv1.x*bv1.x + bv1.y*bv1.y + bv1.z*bv1.z + bv1.w*bv1.w;

        __syncthreads();
        const int kk = kq * 4;
        lA[kk+0][rowm]    = av0.x; lA[kk+1][rowm]    = av0.y;
        lA[kk+2][rowm]    = av0.z; lA[kk+3][rowm]    = av0.w;
        lA[kk+0][rowm+64] = av1.x; lA[kk+1][rowm+64] = av1.y;
        lA[kk+2][rowm+64] = av1.z; lA[kk+3][rowm+64] = av1.w;
        lB[kk+0][rowm]    = bv0.x; lB[kk+1][rowm]    = bv0.y;
        lB[kk+2][rowm]    = bv0.z; lB[kk+3][rowm]    = bv0.w;
        lB[kk+0][rowm+64] = bv1.x; lB[kk+1][rowm+64] = bv1.y;
        lB[kk+2][rowm+64] = bv1.z; lB[kk+3][rowm+64] = bv1.w;
        __syncthreads();

#pragma unroll
        for (int k = 0; k < BK; ++k) {
            const float4 a0 = *(const float4*)&lA[k][r0];
            const float4 a1 = *(const float4*)&lA[k][r0 + 4];
            const float4 b0 = *(const float4*)&lB[k][c0];
            const float4 b1 = *(const float4*)&lB[k][c0 + 4];
            const float a[8] = {a0.x,a0.y,a0.z,a0.w,a1.x,a1.y,a1.z,a1.w};
            const float b[8] = {b0.x,b0.y,b0.z,b0.w,b1.x,b1.y,b1.z,b1.w};
#pragma unroll
            for (int i = 0; i < 8; ++i)
#pragma unroll
                for (int j = 0; j < 8; ++j)
                    acc[i][j] = fmaf(a[i], b[j], acc[i][j]);
        }
    }

    // norms: LDS reduce then one global atomic per thread (256 addrs total)
    __syncthreads();
    float* nrm = &lA[0][0];
    nrm[tid] = 0.f;
    __syncthreads();
    atomicAdd(&nrm[rowm],            a2s0);
    atomicAdd(&nrm[rowm + 64],       a2s1);
    atomicAdd(&nrm[128 + rowm],      b2s0);
    atomicAdd(&nrm[128 + rowm + 64], b2s1);
    __syncthreads();
    atomicAdd(&norms[tid], nrm[tid]);

    // partial C tile: plain coalesced stores, no atomics
    float* P = partials + (size_t)blockIdx.x * (128 * 128);
#pragma unroll
    for (int i = 0; i < 8; ++i) {
        float4 v0 = make_float4(acc[i][0], acc[i][1], acc[i][2], acc[i][3]);
        float4 v1 = make_float4(acc[i][4], acc[i][5], acc[i][6], acc[i][7]);
        *(float4*)&P[(size_t)(r0 + i) * 128 + c0]     = v0;
        *(float4*)&P[(size_t)(r0 + i) * 128 + c0 + 4] = v1;
    }
}

// ---------------- fallback: original atomic-combine version ------------------
__global__ __launch_bounds__(256)
void dot_norm_atomic(const float* __restrict__ Z, const float* __restrict__ Y,
                     float* __restrict__ dots, float* __restrict__ norms,
                     int KC) {
    __shared__ float lA[BK][LSTR];
    __shared__ float lB[BK][LSTR];
    const int tid = threadIdx.x;
    const int tx = tid & 15, ty = tid >> 4;
    const int r0 = ty * 8, c0 = tx * 8;
    const int rowm = tid >> 2, kq = tid & 3;
    float acc[8][8];
#pragma unroll
    for (int i = 0; i < 8; ++i)
#pragma unroll
        for (int j = 0; j < 8; ++j) acc[i][j] = 0.f;
    float a2s0 = 0.f, a2s1 = 0.f, b2s0 = 0.f, b2s1 = 0.f;
    const size_t kbase = (size_t)blockIdx.x * KC;
    const size_t offA0 = (size_t)rowm * DIMD + kbase + kq * 4;
    const size_t offA1 = (size_t)(rowm + 64) * DIMD + kbase + kq * 4;
    const int niter = KC / BK;
#pragma unroll 1
    for (int t = 0; t < niter; ++t) {
        const size_t ko = (size_t)t * BK;
        const float4 av0 = *(const float4*)(Z + offA0 + ko);
        const float4 av1 = *(const float4*)(Z + offA1 + ko);
        const float4 bv0 = *(const float4*)(Y + offA0 + ko);
        const float4 bv1 = *(const float4*)(Y + offA1 + ko);
        a2s0 += av0.x*av0.x + av0.y*av0.y + av0.z*av0.z + av0.w*av0.w;
        a2s1 += av1.x*av1.x + av1.y*av1.y + av1.z*av1.z + av1.w*av1.w;
        b2s0 += bv0.x*bv0.x + bv0.y*bv0.y + bv0.z*bv0.z + bv0.w*bv0.w;
        b2s1 += bv1.x*bv1.x + bv1.y*bv1.y + bv1.z*bv1.z + bv1.w*bv1.w;
        __syncthreads();
        const int kk = kq * 4;
        lA[kk+0][rowm]    = av0.x; lA[kk+1][rowm]    = av0.y;
        lA[kk+2][rowm]    = av0.z; lA[kk+3][rowm]    = av0.w;
        lA[kk+0][rowm+64] = av1.x; lA[kk+1][rowm+64] = av1.y;
        lA[kk+2][rowm+64] = av1.z; lA[kk+3][rowm+64] = av1.w;
        lB[kk+0][rowm]    = bv0.x; lB[kk+1][rowm]    = bv0.y;
        lB[kk+2][rowm]    = bv0.z; lB[kk+3][rowm]    = bv0.w;
        lB[kk+0][rowm+64] = bv1.x; lB[kk+1][rowm+64] = bv1.y;
        lB[kk+2][rowm+64] = bv1.z; lB[kk+3][rowm+64] = bv1.w;
        __syncthreads();
#pragma unroll
        for (int k = 0; k < BK; ++k) {
            const float4 a0 = *(const float4*)&lA[k][r0];
            const float4 a1 = *(const float4*)&lA[k][r0 + 4];
            const float4 b0 = *(const float4*)&lB[k][c0];
            const float4 b1 = *(const float4*)&lB[k][c0 + 4];
            const float a[8] = {a0.x,a0.y,a0.z,a0.w,a1.x,a1.y,a1.z,a1.w};
            const float b[8] = {b0.x,b0.y,b0.z,b0.w,b1.x,b1.y,b1.z,b1.w};
#pragma unroll
            for (int i = 0; i < 8; ++i)
#pragma unroll
                for (int j = 0; j < 8; ++j)
                    acc[i][j] = fmaf(a[i], b[j], acc[i][j]);
        }
    }
    __syncthreads();
    float* nrm = &lA[0][0];
    nrm[tid] = 0.f;
    __syncthreads();
    atomicAdd(&nrm[rowm],            a2s0);
    atomicAdd(&nrm[rowm + 64],       a2s1);
    atomicAdd(&nrm[128 + rowm],      b2s0);
    atomicAdd(&nrm[128 + rowm + 64], b2s1);
    __syncthreads();
    atomicAdd(&norms[tid], nrm[tid]);
#pragma unroll
    for (int i = 0; i < 8; ++i)
#pragma unroll
        for (int j = 0; j < 8; ++j)
            atomicAdd(&dots[(size_t)(r0 + i) * 128 + (c0 + j)], acc[i][j]);
}

// ---------------- reduce: dots = sum_p partials[p] ---------------------------
__global__ __launch_bounds__(256)
void reduce_kernel(const float* __restrict__ partials, float* __restrict__ dots,
                   int P) {
    const int idx4 = blockIdx.x * blockDim.x + threadIdx.x;  // 0..4095 (float4)
    const float4* p = (const float4*)partials;
    float4 s = make_float4(0.f, 0.f, 0.f, 0.f);
    for (int k = 0; k < P; ++k) {
        const float4 v = p[(size_t)k * 4096 + idx4];
        s.x += v.x; s.y += v.y; s.z += v.z; s.w += v.w;
    }
    ((float4*)dots)[idx4] = s;
}

// ---------------- finalize: rank diag per sim row ----------------------------
__global__ void finalize_kernel(const float* __restrict__ dots,
                                const float* __restrict__ norms,
                                float* __restrict__ out) {
    __shared__ int c1, c10;
    const int a = threadIdx.x;   // row of sim (Y side)
    if (a == 0) { c1 = 0; c10 = 0; }
    __syncthreads();
    const float yna = sqrtf(norms[128 + a]);
    const float va  = dots[(size_t)a * 128 + a] / fmaxf(sqrtf(norms[a]) * yna, 1e-8f);
    int cnt = 0;
    for (int b = 0; b < 128; ++b) {
        const float vb = dots[(size_t)b * 128 + a] / fmaxf(sqrtf(norms[b]) * yna, 1e-8f);
        cnt += (b != a && vb > va) ? 1 : 0;
    }
    atomicAdd(&c1,  (cnt == 0) ? 1 : 0);
    atomicAdd(&c10, (cnt < 10) ? 1 : 0);
    __syncthreads();
    if (a == 0) {
        out[0] = (float)c1  / 128.0f;
        out[1] = (float)c10 / 128.0f;
    }
}

extern "C" void kernel_launch(void* const* d_in, const int* in_sizes, int n_in,
                              void* d_out, int out_size, void* d_ws, size_t ws_size,
                              hipStream_t stream) {
    const float* Z = (const float*)d_in[0];
    const float* Y = (const float*)d_in[1];
    float* dots     = (float*)d_ws;            // 16384 floats
    float* norms    = dots + 128 * 128;        // 256 floats
    float* partials = norms + 256;             // NBLK * 16384 floats
    float* out      = (float*)d_out;

    const size_t base_bytes = (size_t)(128 * 128 + 256) * sizeof(float);

    // pick largest split-K factor the workspace can hold (ws_size is constant
    // across calls, so every call does identical work)
    int nb = 0;
    const int cands[4] = {1024, 512, 256, 128};
    for (int c = 0; c < 4; ++c) {
        if (base_bytes + (size_t)cands[c] * 128 * 128 * sizeof(float) <= ws_size) {
            nb = cands[c];
            break;
        }
    }

    // norms (and dots on the fallback path) need zeroing — ws is re-poisoned
    hipMemsetAsync(d_ws, 0, base_bytes, stream);

    if (nb > 0) {
        dot_norm_partial<<<nb, 256, 0, stream>>>(Z, Y, partials, norms, DIMD / nb);
        reduce_kernel<<<16, 256, 0, stream>>>(partials, dots, nb);
    } else {
        dot_norm_atomic<<<512, 256, 0, stream>>>(Z, Y, dots, norms, DIMD / 512);
    }
    finalize_kernel<<<1, 128, 0, stream>>>(dots, norms, out);
}

// Round 4
// 455.617 us; speedup vs baseline: 1.5196x; 1.5196x over previous
//
#include <hip/hip_runtime.h>
#include <hip/hip_bf16.h>
#include <math.h>

// B=128 rows, D=512*512=262144. dots[i][j]=X[i]·Y[j]; sim[j][i]=dots/(|X_i||Y_j|);
// outputs top1/top10 retrieval accuracy. Exact fp32 path (absmax 0 in R2/R3).
//
// R3 post-mortem: reduce_kernel was 355us (16 blocks = 4096 threads, latency-bound,
// 0.7% occupancy); main GEMM ~330us at 2 blocks/CU, VALUBusy 14% (= the 55us fp32
// FMA floor stretched by latency). R4: NBLK->1024 (4 blocks/CU), double-buffered
// LDS with ONE barrier per K-tile, and a two-stage fully-parallel reduce with no
// atomics on the dots path.

#define DIMD 262144
#define BK   16
#define LSTR 132   // LDS row stride: float4-aligned + bank rotation

// ---------------- main GEMM: one block = one K-chunk, full 128x128 C tile ----
__global__ __launch_bounds__(256)
void dot_norm_partial(const float* __restrict__ Z, const float* __restrict__ Y,
                      float* __restrict__ partials, float* __restrict__ norms,
                      int KC) {
    __shared__ float lA[2][BK][LSTR];   // 2 x 8.45 KB
    __shared__ float lB[2][BK][LSTR];   // total 33.8 KB -> 4 blocks/CU

    const int tid = threadIdx.x;
    const int tx = tid & 15;
    const int ty = tid >> 4;
    const int r0 = ty * 8;
    const int c0 = tx * 8;
    const int rowm = tid >> 2;   // 0..63 (second slot rowm+64)
    const int kq   = tid & 3;
    const int kk   = kq * 4;

    float acc[8][8];
#pragma unroll
    for (int i = 0; i < 8; ++i)
#pragma unroll
        for (int j = 0; j < 8; ++j) acc[i][j] = 0.f;

    float a2s0 = 0.f, a2s1 = 0.f, b2s0 = 0.f, b2s1 = 0.f;

    const size_t kbase = (size_t)blockIdx.x * KC;
    const size_t offA0 = (size_t)rowm * DIMD + kbase + kk;
    const size_t offA1 = (size_t)(rowm + 64) * DIMD + kbase + kk;
    const int niter = KC / BK;

    // prologue: tile 0 -> regs -> buf 0
    float4 av0 = *(const float4*)(Z + offA0);
    float4 av1 = *(const float4*)(Z + offA1);
    float4 bv0 = *(const float4*)(Y + offA0);
    float4 bv1 = *(const float4*)(Y + offA1);
    a2s0 += av0.x*av0.x + av0.y*av0.y + av0.z*av0.z + av0.w*av0.w;
    a2s1 += av1.x*av1.x + av1.y*av1.y + av1.z*av1.z + av1.w*av1.w;
    b2s0 += bv0.x*bv0.x + bv0.y*bv0.y + bv0.z*bv0.z + bv0.w*bv0.w;
    b2s1 += bv1.x*bv1.x + bv1.y*bv1.y + bv1.z*bv1.z + bv1.w*bv1.w;
    lA[0][kk+0][rowm]    = av0.x; lA[0][kk+1][rowm]    = av0.y;
    lA[0][kk+2][rowm]    = av0.z; lA[0][kk+3][rowm]    = av0.w;
    lA[0][kk+0][rowm+64] = av1.x; lA[0][kk+1][rowm+64] = av1.y;
    lA[0][kk+2][rowm+64] = av1.z; lA[0][kk+3][rowm+64] = av1.w;
    lB[0][kk+0][rowm]    = bv0.x; lB[0][kk+1][rowm]    = bv0.y;
    lB[0][kk+2][rowm]    = bv0.z; lB[0][kk+3][rowm]    = bv0.w;
    lB[0][kk+0][rowm+64] = bv1.x; lB[0][kk+1][rowm+64] = bv1.y;
    lB[0][kk+2][rowm+64] = bv1.z; lB[0][kk+3][rowm+64] = bv1.w;
    __syncthreads();

#pragma unroll 1
    for (int t = 0; t < niter; ++t) {
        const int cur = t & 1;
        const bool more = (t + 1) < niter;
        if (more) {   // issue next tile's global loads before compute
            const size_t ko = (size_t)(t + 1) * BK;
            av0 = *(const float4*)(Z + offA0 + ko);
            av1 = *(const float4*)(Z + offA1 + ko);
            bv0 = *(const float4*)(Y + offA0 + ko);
            bv1 = *(const float4*)(Y + offA1 + ko);
        }

#pragma unroll
        for (int k = 0; k < BK; ++k) {
            const float4 a0 = *(const float4*)&lA[cur][k][r0];
            const float4 a1 = *(const float4*)&lA[cur][k][r0 + 4];
            const float4 b0 = *(const float4*)&lB[cur][k][c0];
            const float4 b1 = *(const float4*)&lB[cur][k][c0 + 4];
            const float a[8] = {a0.x,a0.y,a0.z,a0.w,a1.x,a1.y,a1.z,a1.w};
            const float b[8] = {b0.x,b0.y,b0.z,b0.w,b1.x,b1.y,b1.z,b1.w};
#pragma unroll
            for (int i = 0; i < 8; ++i)
#pragma unroll
                for (int j = 0; j < 8; ++j)
                    acc[i][j] = fmaf(a[i], b[j], acc[i][j]);
        }

        if (more) {
            const int nxt = 1 - cur;
            a2s0 += av0.x*av0.x + av0.y*av0.y + av0.z*av0.z + av0.w*av0.w;
            a2s1 += av1.x*av1.x + av1.y*av1.y + av1.z*av1.z + av1.w*av1.w;
            b2s0 += bv0.x*bv0.x + bv0.y*bv0.y + bv0.z*bv0.z + bv0.w*bv0.w;
            b2s1 += bv1.x*bv1.x + bv1.y*bv1.y + bv1.z*bv1.z + bv1.w*bv1.w;
            lA[nxt][kk+0][rowm]    = av0.x; lA[nxt][kk+1][rowm]    = av0.y;
            lA[nxt][kk+2][rowm]    = av0.z; lA[nxt][kk+3][rowm]    = av0.w;
            lA[nxt][kk+0][rowm+64] = av1.x; lA[nxt][kk+1][rowm+64] = av1.y;
            lA[nxt][kk+2][rowm+64] = av1.z; lA[nxt][kk+3][rowm+64] = av1.w;
            lB[nxt][kk+0][rowm]    = bv0.x; lB[nxt][kk+1][rowm]    = bv0.y;
            lB[nxt][kk+2][rowm]    = bv0.z; lB[nxt][kk+3][rowm]    = bv0.w;
            lB[nxt][kk+0][rowm+64] = bv1.x; lB[nxt][kk+1][rowm+64] = bv1.y;
            lB[nxt][kk+2][rowm+64] = bv1.z; lB[nxt][kk+3][rowm+64] = bv1.w;
            __syncthreads();
        }
    }

    // norms: LDS reduce then one global atomic per thread (256 addrs total)
    __syncthreads();
    float* nrm = &lA[0][0][0];
    nrm[tid] = 0.f;
    __syncthreads();
    atomicAdd(&nrm[rowm],            a2s0);
    atomicAdd(&nrm[rowm + 64],       a2s1);
    atomicAdd(&nrm[128 + rowm],      b2s0);
    atomicAdd(&nrm[128 + rowm + 64], b2s1);
    __syncthreads();
    atomicAdd(&norms[tid], nrm[tid]);

    // partial C tile: plain coalesced stores, no atomics
    float* P = partials + (size_t)blockIdx.x * (128 * 128);
#pragma unroll
    for (int i = 0; i < 8; ++i) {
        float4 v0 = make_float4(acc[i][0], acc[i][1], acc[i][2], acc[i][3]);
        float4 v1 = make_float4(acc[i][4], acc[i][5], acc[i][6], acc[i][7]);
        *(float4*)&P[(size_t)(r0 + i) * 128 + c0]     = v0;
        *(float4*)&P[(size_t)(r0 + i) * 128 + c0 + 4] = v1;
    }
}

// ---------------- fallback: atomic-combine version (tiny ws) -----------------
__global__ __launch_bounds__(256)
void dot_norm_atomic(const float* __restrict__ Z, const float* __restrict__ Y,
                     float* __restrict__ dots, float* __restrict__ norms,
                     int KC) {
    __shared__ float lA[BK][LSTR];
    __shared__ float lB[BK][LSTR];
    const int tid = threadIdx.x;
    const int tx = tid & 15, ty = tid >> 4;
    const int r0 = ty * 8, c0 = tx * 8;
    const int rowm = tid >> 2, kq = tid & 3;
    float acc[8][8];
#pragma unroll
    for (int i = 0; i < 8; ++i)
#pragma unroll
        for (int j = 0; j < 8; ++j) acc[i][j] = 0.f;
    float a2s0 = 0.f, a2s1 = 0.f, b2s0 = 0.f, b2s1 = 0.f;
    const size_t kbase = (size_t)blockIdx.x * KC;
    const size_t offA0 = (size_t)rowm * DIMD + kbase + kq * 4;
    const size_t offA1 = (size_t)(rowm + 64) * DIMD + kbase + kq * 4;
    const int niter = KC / BK;
#pragma unroll 1
    for (int t = 0; t < niter; ++t) {
        const size_t ko = (size_t)t * BK;
        const float4 av0 = *(const float4*)(Z + offA0 + ko);
        const float4 av1 = *(const float4*)(Z + offA1 + ko);
        const float4 bv0 = *(const float4*)(Y + offA0 + ko);
        const float4 bv1 = *(const float4*)(Y + offA1 + ko);
        a2s0 += av0.x*av0.x + av0.y*av0.y + av0.z*av0.z + av0.w*av0.w;
        a2s1 += av1.x*av1.x + av1.y*av1.y + av1.z*av1.z + av1.w*av1.w;
        b2s0 += bv0.x*bv0.x + bv0.y*bv0.y + bv0.z*bv0.z + bv0.w*bv0.w;
        b2s1 += bv1.x*bv1.x + bv1.y*bv1.y + bv1.z*bv1.z + bv1.w*bv1.w;
        __syncthreads();
        const int kk = kq * 4;
        lA[kk+0][rowm]    = av0.x; lA[kk+1][rowm]    = av0.y;
        lA[kk+2][rowm]    = av0.z; lA[kk+3][rowm]    = av0.w;
        lA[kk+0][rowm+64] = av1.x; lA[kk+1][rowm+64] = av1.y;
        lA[kk+2][rowm+64] = av1.z; lA[kk+3][rowm+64] = av1.w;
        lB[kk+0][rowm]    = bv0.x; lB[kk+1][rowm]    = bv0.y;
        lB[kk+2][rowm]    = bv0.z; lB[kk+3][rowm]    = bv0.w;
        lB[kk+0][rowm+64] = bv1.x; lB[kk+1][rowm+64] = bv1.y;
        lB[kk+2][rowm+64] = bv1.z; lB[kk+3][rowm+64] = bv1.w;
        __syncthreads();
#pragma unroll
        for (int k = 0; k < BK; ++k) {
            const float4 a0 = *(const float4*)&lA[k][r0];
            const float4 a1 = *(const float4*)&lA[k][r0 + 4];
            const float4 b0 = *(const float4*)&lB[k][c0];
            const float4 b1 = *(const float4*)&lB[k][c0 + 4];
            const float a[8] = {a0.x,a0.y,a0.z,a0.w,a1.x,a1.y,a1.z,a1.w};
            const float b[8] = {b0.x,b0.y,b0.z,b0.w,b1.x,b1.y,b1.z,b1.w};
#pragma unroll
            for (int i = 0; i < 8; ++i)
#pragma unroll
                for (int j = 0; j < 8; ++j)
                    acc[i][j] = fmaf(a[i], b[j], acc[i][j]);
        }
    }
    __syncthreads();
    float* nrm = &lA[0][0];
    nrm[tid] = 0.f;
    __syncthreads();
    atomicAdd(&nrm[rowm],            a2s0);
    atomicAdd(&nrm[rowm + 64],       a2s1);
    atomicAdd(&nrm[128 + rowm],      b2s0);
    atomicAdd(&nrm[128 + rowm + 64], b2s1);
    __syncthreads();
    atomicAdd(&norms[tid], nrm[tid]);
#pragma unroll
    for (int i = 0; i < 8; ++i)
#pragma unroll
        for (int j = 0; j < 8; ++j)
            atomicAdd(&dots[(size_t)(r0 + i) * 128 + (c0 + j)], acc[i][j]);
}

// ---------------- reduce stage 1: NBLK partials -> 32 chunk-sums -------------
// grid 512x256 = 131072 threads: g -> (chunk = g>>12 in [0,32), f4 = g&4095)
__global__ __launch_bounds__(256)
void reduce_stage1(const float* __restrict__ partials, float* __restrict__ stage,
                   int per_chunk) {
    const int g = blockIdx.x * 256 + threadIdx.x;
    const int f4 = g & 4095;
    const int chunk = g >> 12;
    const float4* p = (const float4*)partials;
    float4 s = make_float4(0.f, 0.f, 0.f, 0.f);
    const size_t base = (size_t)chunk * per_chunk;
    for (int k = 0; k < per_chunk; ++k) {
        const float4 v = p[(base + k) * 4096 + f4];
        s.x += v.x; s.y += v.y; s.z += v.z; s.w += v.w;
    }
    ((float4*)stage)[(size_t)chunk * 4096 + f4] = s;
}

// ---------------- reduce stage 2: 32 chunk-sums -> dots ----------------------
// grid 16x256 = 4096 threads, one float4 each (2 MB input, L2/L3-hot)
__global__ __launch_bounds__(256)
void reduce_stage2(const float* __restrict__ stage, float* __restrict__ dots) {
    const int f4 = blockIdx.x * 256 + threadIdx.x;
    const float4* p = (const float4*)stage;
    float4 s = make_float4(0.f, 0.f, 0.f, 0.f);
#pragma unroll
    for (int c = 0; c < 32; ++c) {
        const float4 v = p[(size_t)c * 4096 + f4];
        s.x += v.x; s.y += v.y; s.z += v.z; s.w += v.w;
    }
    ((float4*)dots)[f4] = s;
}

// ---------------- finalize: rank diag per sim row ----------------------------
__global__ void finalize_kernel(const float* __restrict__ dots,
                                const float* __restrict__ norms,
                                float* __restrict__ out) {
    __shared__ int c1, c10;
    const int a = threadIdx.x;   // row of sim (Y side)
    if (a == 0) { c1 = 0; c10 = 0; }
    __syncthreads();
    const float yna = sqrtf(norms[128 + a]);
    const float va  = dots[(size_t)a * 128 + a] / fmaxf(sqrtf(norms[a]) * yna, 1e-8f);
    int cnt = 0;
    for (int b = 0; b < 128; ++b) {
        const float vb = dots[(size_t)b * 128 + a] / fmaxf(sqrtf(norms[b]) * yna, 1e-8f);
        cnt += (b != a && vb > va) ? 1 : 0;
    }
    atomicAdd(&c1,  (cnt == 0) ? 1 : 0);
    atomicAdd(&c10, (cnt < 10) ? 1 : 0);
    __syncthreads();
    if (a == 0) {
        out[0] = (float)c1  / 128.0f;
        out[1] = (float)c10 / 128.0f;
    }
}

extern "C" void kernel_launch(void* const* d_in, const int* in_sizes, int n_in,
                              void* d_out, int out_size, void* d_ws, size_t ws_size,
                              hipStream_t stream) {
    const float* Z = (const float*)d_in[0];
    const float* Y = (const float*)d_in[1];
    float* dots     = (float*)d_ws;                 // 16384 floats
    float* norms    = dots + 128 * 128;             // 256 floats
    float* stage    = norms + 256;                  // 32*16384 = 524288 floats
    float* partials = stage + 32 * 16384;           // NBLK * 16384 floats
    float* out      = (float*)d_out;

    const size_t head_floats = 128 * 128 + 256 + 32 * 16384;

    // pick largest split-K factor the workspace can hold (ws_size constant
    // across calls -> identical work every call)
    int nb = 0;
    const int cands[4] = {1024, 512, 256, 128};
    for (int c = 0; c < 4; ++c) {
        if ((head_floats + (size_t)cands[c] * 16384) * sizeof(float) <= ws_size) {
            nb = cands[c];
            break;
        }
    }

    // norms (and fallback dots) accumulate via atomics — zero them
    hipMemsetAsync(d_ws, 0, (128 * 128 + 256) * sizeof(float), stream);

    if (nb > 0) {
        dot_norm_partial<<<nb, 256, 0, stream>>>(Z, Y, partials, norms, DIMD / nb);
        reduce_stage1<<<512, 256, 0, stream>>>(partials, stage, nb / 32);
        reduce_stage2<<<16, 256, 0, stream>>>(stage, dots);
    } else {
        dot_norm_atomic<<<512, 256, 0, stream>>>(Z, Y, dots, norms, DIMD / 512);
    }
    finalize_kernel<<<1, 128, 0, stream>>>(dots, norms, out);
}

// Round 5
// 358.979 us; speedup vs baseline: 1.9286x; 1.2692x over previous
//
#include <hip/hip_runtime.h>
#include <hip/hip_bf16.h>
#include <math.h>

// B=128 rows, D=512*512=262144. dots[i][j]=Z[i]·Y[j]; sim[a][b]=dots[b][a]/
// max(xn[b]*yn[a],eps); outputs top1/top10 retrieval accuracy.
//
// R5: fp32-VALU path hit its structural floor (VALUBusy 33% of 252us = the
// 55us fp32 FMA floor + latency). Switch to split-bf16 MFMA:
//   a = a_hi + a_lo (bf16 truncation), dot = hi*hi + hi*lo + lo*hi
// residual ~2^-16/term -> sim error ~1e-7 << rank gaps ~1e-4 -> exact ranking.
// mfma_f32_16x16x32_bf16, doc-verified layouts (m89/m91/m92):
//   A: m=lane&15, k=(lane>>4)*8+j ; C/D: col=lane&15, row=(lane>>4)*4+reg.

#define DIMD 262144

typedef short  bf16x8  __attribute__((ext_vector_type(8)));   // 8 bf16 = 4 VGPR
typedef float  floatx4 __attribute__((ext_vector_type(4)));   // C/D frag

union FragU { uint4 u; bf16x8 v; };

// ---------------- main: split-bf16 MFMA GEMM, split-K partials ---------------
// grid nb blocks x 256 thr (4 waves). Block owns orig-K chunk of NT*32.
// LDS planes: [0]=Z_hi [1]=Z_lo [2]=Y_hi [3]=Y_lo, 128 rows x 32 k (bf16),
// row stride 40 ushorts = 80 B (20-bank rotation -> 2-way, free).
__global__ __launch_bounds__(256, 3)
void mfma_dot_kernel(const float* __restrict__ Z, const float* __restrict__ Y,
                     float* __restrict__ partials, float* __restrict__ norms,
                     int NT) {
    __shared__ __align__(16) ushort planes[4][128][40];  // 40960 B
    __shared__ float nrm[256];                           // Z rows, then Y rows

    const int tid = threadIdx.x;
    const int lid = tid & 63;
    const int w   = tid >> 6;

    // staging: thread -> rows {32i + srow}, float4 q within 32-k tile
    const int srow = tid >> 3;    // 0..31
    const int q    = tid & 7;     // 0..7

    // mfma: wave w owns C rows [m0,m0+64) x cols [n0,n0+64)
    const int m0 = 64 * (w & 1);
    const int n0 = 64 * (w >> 1);
    const int fr = lid & 15;            // fragment row (m or n)
    const int fk = (lid >> 4) * 8;      // k offset in ushorts

    floatx4 acc[4][4];
#pragma unroll
    for (int a = 0; a < 4; ++a)
#pragma unroll
        for (int b = 0; b < 4; ++b)
            acc[a][b] = (floatx4){0.f, 0.f, 0.f, 0.f};

    nrm[tid] = 0.f;   // visible after first barrier

    const size_t kbase = (size_t)blockIdx.x * ((size_t)NT * 32);
    size_t off[4];
#pragma unroll
    for (int i = 0; i < 4; ++i)
        off[i] = (size_t)(32 * i + srow) * DIMD + kbase + 4 * q;

    float4 zr[4], yr[4];
#pragma unroll
    for (int i = 0; i < 4; ++i) zr[i] = *(const float4*)(Z + off[i]);
#pragma unroll
    for (int i = 0; i < 4; ++i) yr[i] = *(const float4*)(Y + off[i]);

#pragma unroll 1
    for (int t = 0; t < NT; ++t) {
        __syncthreads();   // prev tile's readers done; t=0: nrm zero visible

        // ---- convert fp32 -> (hi,lo) bf16, store planes, accumulate norms
#pragma unroll
        for (int i = 0; i < 4; ++i) {
            const float4 v = zr[i];
            const uint h0 = __float_as_uint(v.x) >> 16, h1 = __float_as_uint(v.y) >> 16;
            const uint h2 = __float_as_uint(v.z) >> 16, h3 = __float_as_uint(v.w) >> 16;
            const uint l0 = __float_as_uint(v.x - __uint_as_float(h0 << 16)) >> 16;
            const uint l1 = __float_as_uint(v.y - __uint_as_float(h1 << 16)) >> 16;
            const uint l2 = __float_as_uint(v.z - __uint_as_float(h2 << 16)) >> 16;
            const uint l3 = __float_as_uint(v.w - __uint_as_float(h3 << 16)) >> 16;
            *(uint2*)&planes[0][32 * i + srow][4 * q] =
                make_uint2(h0 | (h1 << 16), h2 | (h3 << 16));
            *(uint2*)&planes[1][32 * i + srow][4 * q] =
                make_uint2(l0 | (l1 << 16), l2 | (l3 << 16));
            const float s = v.x * v.x + v.y * v.y + v.z * v.z + v.w * v.w;
            atomicAdd(&nrm[32 * i + srow], s);
        }
#pragma unroll
        for (int i = 0; i < 4; ++i) {
            const float4 v = yr[i];
            const uint h0 = __float_as_uint(v.x) >> 16, h1 = __float_as_uint(v.y) >> 16;
            const uint h2 = __float_as_uint(v.z) >> 16, h3 = __float_as_uint(v.w) >> 16;
            const uint l0 = __float_as_uint(v.x - __uint_as_float(h0 << 16)) >> 16;
            const uint l1 = __float_as_uint(v.y - __uint_as_float(h1 << 16)) >> 16;
            const uint l2 = __float_as_uint(v.z - __uint_as_float(h2 << 16)) >> 16;
            const uint l3 = __float_as_uint(v.w - __uint_as_float(h3 << 16)) >> 16;
            *(uint2*)&planes[2][32 * i + srow][4 * q] =
                make_uint2(h0 | (h1 << 16), h2 | (h3 << 16));
            *(uint2*)&planes[3][32 * i + srow][4 * q] =
                make_uint2(l0 | (l1 << 16), l2 | (l3 << 16));
            const float s = v.x * v.x + v.y * v.y + v.z * v.z + v.w * v.w;
            atomicAdd(&nrm[128 + 32 * i + srow], s);
        }

        // ---- issue next tile's global loads (in flight through MFMA phase)
        if (t + 1 < NT) {
            const size_t ko = (size_t)(t + 1) * 32;
#pragma unroll
            for (int i = 0; i < 4; ++i) zr[i] = *(const float4*)(Z + off[i] + ko);
#pragma unroll
            for (int i = 0; i < 4; ++i) yr[i] = *(const float4*)(Y + off[i] + ko);
        }

        __syncthreads();   // planes ready

        // ---- fragments + 48 MFMAs (16 tiles x 3 products)
        FragU bh[4], bl[4];
#pragma unroll
        for (int tn = 0; tn < 4; ++tn) {
            bh[tn].u = *(const uint4*)&planes[2][n0 + 16 * tn + fr][fk];
            bl[tn].u = *(const uint4*)&planes[3][n0 + 16 * tn + fr][fk];
        }
#pragma unroll
        for (int tm = 0; tm < 4; ++tm) {
            FragU ah, al;
            ah.u = *(const uint4*)&planes[0][m0 + 16 * tm + fr][fk];
            al.u = *(const uint4*)&planes[1][m0 + 16 * tm + fr][fk];
#pragma unroll
            for (int tn = 0; tn < 4; ++tn) {
                acc[tm][tn] = __builtin_amdgcn_mfma_f32_16x16x32_bf16(ah.v, bh[tn].v, acc[tm][tn], 0, 0, 0);
                acc[tm][tn] = __builtin_amdgcn_mfma_f32_16x16x32_bf16(ah.v, bl[tn].v, acc[tm][tn], 0, 0, 0);
                acc[tm][tn] = __builtin_amdgcn_mfma_f32_16x16x32_bf16(al.v, bh[tn].v, acc[tm][tn], 0, 0, 0);
            }
        }
    }

    __syncthreads();
    atomicAdd(&norms[tid], nrm[tid]);   // 256 addrs, 1024 adds each — cheap

    // partial C tile: C/D layout col=lane&15, row=(lane>>4)*4+reg
    float* P = partials + (size_t)blockIdx.x * 16384;
    const int rq = (lid >> 4) * 4;
#pragma unroll
    for (int tm = 0; tm < 4; ++tm)
#pragma unroll
        for (int tn = 0; tn < 4; ++tn)
#pragma unroll
            for (int r = 0; r < 4; ++r)
                P[(size_t)(m0 + 16 * tm + rq + r) * 128 + (n0 + 16 * tn + fr)] =
                    acc[tm][tn][r];
}

// ---------------- fallback: fp32 atomic-combine (tiny ws only) ---------------
#define BK   16
#define LSTR 132
__global__ __launch_bounds__(256)
void dot_norm_atomic(const float* __restrict__ Z, const float* __restrict__ Y,
                     float* __restrict__ dots, float* __restrict__ norms,
                     int KC) {
    __shared__ float lA[BK][LSTR];
    __shared__ float lB[BK][LSTR];
    const int tid = threadIdx.x;
    const int tx = tid & 15, ty = tid >> 4;
    const int r0 = ty * 8, c0 = tx * 8;
    const int rowm = tid >> 2, kq = tid & 3;
    float acc[8][8];
#pragma unroll
    for (int i = 0; i < 8; ++i)
#pragma unroll
        for (int j = 0; j < 8; ++j) acc[i][j] = 0.f;
    float a2s0 = 0.f, a2s1 = 0.f, b2s0 = 0.f, b2s1 = 0.f;
    const size_t kbase = (size_t)blockIdx.x * KC;
    const size_t offA0 = (size_t)rowm * DIMD + kbase + kq * 4;
    const size_t offA1 = (size_t)(rowm + 64) * DIMD + kbase + kq * 4;
    const int niter = KC / BK;
#pragma unroll 1
    for (int t = 0; t < niter; ++t) {
        const size_t ko = (size_t)t * BK;
        const float4 av0 = *(const float4*)(Z + offA0 + ko);
        const float4 av1 = *(const float4*)(Z + offA1 + ko);
        const float4 bv0 = *(const float4*)(Y + offA0 + ko);
        const float4 bv1 = *(const float4*)(Y + offA1 + ko);
        a2s0 += av0.x*av0.x + av0.y*av0.y + av0.z*av0.z + av0.w*av0.w;
        a2s1 += av1.x*av1.x + av1.y*av1.y + av1.z*av1.z + av1.w*av1.w;
        b2s0 += bv0.x*bv0.x + bv0.y*bv0.y + bv0.z*bv0.z + bv0.w*bv0.w;
        b2s1 += bv1.x*bv1.x + bv1.y*bv1.y + bv1.z*bv1.z + bv1.w*bv1.w;
        __syncthreads();
        const int kk = kq * 4;
        lA[kk+0][rowm]    = av0.x; lA[kk+1][rowm]    = av0.y;
        lA[kk+2][rowm]    = av0.z; lA[kk+3][rowm]    = av0.w;
        lA[kk+0][rowm+64] = av1.x; lA[kk+1][rowm+64] = av1.y;
        lA[kk+2][rowm+64] = av1.z; lA[kk+3][rowm+64] = av1.w;
        lB[kk+0][rowm]    = bv0.x; lB[kk+1][rowm]    = bv0.y;
        lB[kk+2][rowm]    = bv0.z; lB[kk+3][rowm]    = bv0.w;
        lB[kk+0][rowm+64] = bv1.x; lB[kk+1][rowm+64] = bv1.y;
        lB[kk+2][rowm+64] = bv1.z; lB[kk+3][rowm+64] = bv1.w;
        __syncthreads();
#pragma unroll
        for (int k = 0; k < BK; ++k) {
            const float4 a0 = *(const float4*)&lA[k][r0];
            const float4 a1 = *(const float4*)&lA[k][r0 + 4];
            const float4 b0 = *(const float4*)&lB[k][c0];
            const float4 b1 = *(const float4*)&lB[k][c0 + 4];
            const float a[8] = {a0.x,a0.y,a0.z,a0.w,a1.x,a1.y,a1.z,a1.w};
            const float b[8] = {b0.x,b0.y,b0.z,b0.w,b1.x,b1.y,b1.z,b1.w};
#pragma unroll
            for (int i = 0; i < 8; ++i)
#pragma unroll
                for (int j = 0; j < 8; ++j)
                    acc[i][j] = fmaf(a[i], b[j], acc[i][j]);
        }
    }
    __syncthreads();
    float* nrm = &lA[0][0];
    nrm[tid] = 0.f;
    __syncthreads();
    atomicAdd(&nrm[rowm],            a2s0);
    atomicAdd(&nrm[rowm + 64],       a2s1);
    atomicAdd(&nrm[128 + rowm],      b2s0);
    atomicAdd(&nrm[128 + rowm + 64], b2s1);
    __syncthreads();
    atomicAdd(&norms[tid], nrm[tid]);
#pragma unroll
    for (int i = 0; i < 8; ++i)
#pragma unroll
        for (int j = 0; j < 8; ++j)
            atomicAdd(&dots[(size_t)(r0 + i) * 128 + (c0 + j)], acc[i][j]);
}

// ---------------- reduce stage 1: nb partials -> 32 chunk-sums ---------------
__global__ __launch_bounds__(256)
void reduce_stage1(const float* __restrict__ partials, float* __restrict__ stage,
                   int per_chunk) {
    const int g = blockIdx.x * 256 + threadIdx.x;   // 512 blocks -> 131072
    const int f4 = g & 4095;
    const int chunk = g >> 12;
    const float4* p = (const float4*)partials;
    float4 s = make_float4(0.f, 0.f, 0.f, 0.f);
    const size_t base = (size_t)chunk * per_chunk;
    for (int k = 0; k < per_chunk; ++k) {
        const float4 v = p[(base + k) * 4096 + f4];
        s.x += v.x; s.y += v.y; s.z += v.z; s.w += v.w;
    }
    ((float4*)stage)[(size_t)chunk * 4096 + f4] = s;
}

// ---------------- rank: fused chunk-sum + sim + top1/top10 -------------------
// block a = sim row (Y index), thread b = col (Z index). out must be pre-zeroed.
__global__ __launch_bounds__(128)
void rank_kernel(const float* __restrict__ stage, const float* __restrict__ norms,
                 float* __restrict__ out, int nchunks) {
    __shared__ float sim[128];
    __shared__ int cnt;
    const int a = blockIdx.x;
    const int b = threadIdx.x;
    float s = 0.f;
    for (int c = 0; c < nchunks; ++c)
        s += stage[(size_t)c * 16384 + (size_t)b * 128 + a];
    const float v = s / fmaxf(sqrtf(norms[b]) * sqrtf(norms[128 + a]), 1e-8f);
    sim[b] = v;
    if (b == 0) cnt = 0;
    __syncthreads();
    const float diag = sim[a];
    if (b != a && v > diag) atomicAdd(&cnt, 1);
    __syncthreads();
    if (b == 0) {
        if (cnt == 0) atomicAdd(&out[0], 1.0f / 128.0f);   // k/128 exact in fp32
        if (cnt < 10) atomicAdd(&out[1], 1.0f / 128.0f);
    }
}

extern "C" void kernel_launch(void* const* d_in, const int* in_sizes, int n_in,
                              void* d_out, int out_size, void* d_ws, size_t ws_size,
                              hipStream_t stream) {
    const float* Z = (const float*)d_in[0];
    const float* Y = (const float*)d_in[1];
    float* dots     = (float*)d_ws;            // 16384 (fallback only)
    float* norms    = dots + 128 * 128;        // 256
    float* stage    = norms + 256;             // 32*16384
    float* partials = stage + 32 * 16384;      // nb*16384
    float* out      = (float*)d_out;

    const size_t head_floats = 128 * 128 + 256 + 32 * 16384;
    int nb = 0;
    const int cands[3] = {1024, 512, 256};
    for (int c = 0; c < 3; ++c) {
        if ((head_floats + (size_t)cands[c] * 16384) * sizeof(float) <= ws_size) {
            nb = cands[c];
            break;
        }
    }

    hipMemsetAsync(d_ws, 0, (128 * 128 + 256) * sizeof(float), stream);
    hipMemsetAsync(d_out, 0, 2 * sizeof(float), stream);

    if (nb > 0) {
        mfma_dot_kernel<<<nb, 256, 0, stream>>>(Z, Y, partials, norms,
                                                DIMD / nb / 32);
        reduce_stage1<<<512, 256, 0, stream>>>(partials, stage, nb / 32);
        rank_kernel<<<128, 128, 0, stream>>>(stage, norms, out, 32);
    } else {
        dot_norm_atomic<<<512, 256, 0, stream>>>(Z, Y, dots, norms, DIMD / 512);
        rank_kernel<<<128, 128, 0, stream>>>(dots, norms, out, 1);
    }
}